// Round 1
// 101.800 us; speedup vs baseline: 1.0162x; 1.0162x over previous
//
#include <hip/hip_runtime.h>

// HMM forward, B=8192, TMAX=2048, N=2 states, obs in {0,1}.
// One wave (64 lanes) per sequence.
// R1 (this round): variable chunk width W = ceil(steps/64).
//   - loads + ballots cover exactly W 64-obs words (per-word guard granularity:
//     ~34.6 MB fetched vs 42 MB with the old 512-elem groups)
//   - chain loop trip = W (wave-uniform, avg ~16.5) instead of fixed 32 steps;
//     all 64 lanes near-fully utilized instead of ~50%
//   - ballot words redistributed to lanes via 3 shfl + 64-bit funnel shift
//   - shuffle tree unguarded (shfl_down clamps OOB to self; lane 0's
//     dependency cone never reads a clamped lane -> bit-identical)
//   - readfirstlane(b) -> wave-uniform row base -> scalar loads for T and x0
//   - loads pipelined in 2x8-word buffers (16 VGPR) to stay <=64 VGPR
#define TMAX_C 2048
#define ROWLEN (TMAX_C + 1)

__global__ __launch_bounds__(256, 8) void hmm_fwd_kernel(
    const int* __restrict__ combined,   // (B, TMAX+1): x[0..TMAX-1], T at [TMAX]
    const float* __restrict__ sp,       // (2,)  state prior logits
    const float* __restrict__ tr,       // (2,2) transition logits
    const float* __restrict__ emi,      // (2,2) emission logits
    float* __restrict__ out, int B)
{
    const int lane = threadIdx.x & 63;
    const int b = blockIdx.x * (blockDim.x >> 6) + (threadIdx.x >> 6);
    if (b >= B) return;

    // b is wave-uniform by construction; make it scalar so T/x0 are s_loads.
    const int ub = __builtin_amdgcn_readfirstlane(b);
    const int* __restrict__ row = combined + (size_t)ub * ROWLEN;
    const int T  = row[TMAX_C];          // gates everything; issue first
    const int x0 = row[0];
    const int steps = T - 1;             // matrices applied at t = 1 .. T-1
    const int W = (steps + 63) >> 6;     // per-lane chunk width == #64-obs words, 0..32

    // ---- phase 1: guarded pipelined loads + ballots ----
    // Word w covers obs-step bits [64w, 64w+64); lane loads element 1+64w+lane.
    // All addresses <= 2048 are in-bounds for any T; guards only save BW.
    unsigned wlo = 0u, whi = 0u;         // lane w (w<32) keeps ballot word w
    int A0[8], A1[8];

#define LOADG(g, buf)                                                   \
    do {                                                                \
        _Pragma("unroll")                                               \
        for (int u = 0; u < 8; ++u) {                                   \
            const int w = ((g) << 3) + u;                               \
            if (w < W) (buf)[u] = row[1 + (w << 6) + lane];             \
        }                                                               \
    } while (0)

#define BALLOTG(g, buf)                                                 \
    do {                                                                \
        _Pragma("unroll")                                               \
        for (int u = 0; u < 8; ++u) {                                   \
            const int w = ((g) << 3) + u;                               \
            if (w < W) {                                                \
                const unsigned long long m = __ballot((buf)[u] != 0);   \
                if (lane == w) {                                        \
                    wlo = (unsigned)m;                                  \
                    whi = (unsigned)(m >> 32);                          \
                }                                                       \
            }                                                           \
        }                                                               \
    } while (0)

    LOADG(0, A0);
    LOADG(1, A1);

    // ---- tiny softmaxes (overlap with outstanding loads) ----
    float p0 = __expf(sp[0]), p1 = __expf(sp[1]);
    { float s = p0 + p1; p0 /= s; p1 /= s; }
    float A00, A01, A10, A11;
    { float e0 = __expf(tr[0]), e1 = __expf(tr[1]); float s = e0 + e1; A00 = e0/s; A01 = e1/s; }
    { float e0 = __expf(tr[2]), e1 = __expf(tr[3]); float s = e0 + e1; A10 = e0/s; A11 = e1/s; }
    float em00, em01, em10, em11;   // em[state][obs]
    { float e0 = __expf(emi[0]), e1 = __expf(emi[1]); float s = e0 + e1; em00 = e0/s; em01 = e1/s; }
    { float e0 = __expf(emi[2]), e1 = __expf(emi[3]); float s = e0 + e1; em10 = e0/s; em11 = e1/s; }

    // M_o[i][j] = A[i][j] * em[j][o]   (row-vector convention)
    const float M0_00 = A00*em00, M0_01 = A01*em10, M0_10 = A10*em00, M0_11 = A11*em10;
    const float M1_00 = A00*em01, M1_01 = A01*em11, M1_10 = A10*em01, M1_11 = A11*em11;

    BALLOTG(0, A0);
    LOADG(2, A0);
    BALLOTG(1, A1);
    LOADG(3, A1);
    BALLOTG(2, A0);
    BALLOTG(3, A1);
#undef LOADG
#undef BALLOTG

    // ---- phase 2: redistribute ballot words to per-lane W-bit windows ----
    // Lane L owns global obs-step bits [L*W, L*W+W).
    const int idx = lane * W;            // 0..2016
    const int w0  = idx >> 6;
    const int off = idx & 63;
    const unsigned u0lo = (unsigned)__shfl((int)wlo, w0);
    const unsigned u0hi = (unsigned)__shfl((int)whi, w0);
    const unsigned u1lo = (unsigned)__shfl((int)wlo, w0 + 1);  // lanes >=W hold 0
    const unsigned long long v64 = ((unsigned long long)u0hi << 32) | u0lo;
    unsigned bits = (unsigned)(v64 >> off);
    if (off + W > 64)                    // then off > 32, so 64-off in (0,32)
        bits |= (u1lo << (64 - off));

    int cnt = steps - idx;               // valid obs this lane, clamped to [0,W]
    cnt = cnt < 0 ? 0 : cnt;
    cnt = cnt > W ? W : cnt;

    // ---- phase 3: W-step 2x2 matrix chain (W wave-uniform, avg ~16.5) ----
    float P00 = 1.f, P01 = 0.f, P10 = 0.f, P11 = 1.f;
    #pragma unroll 4
    for (int j = 0; j < W; ++j) {
        const bool bit = (bits >> j) & 1u;
        const float m00 = bit ? M1_00 : M0_00;
        const float m01 = bit ? M1_01 : M0_01;
        const float m10 = bit ? M1_10 : M0_10;
        const float m11 = bit ? M1_11 : M0_11;
        const float n00 = P00*m00 + P01*m10;
        const float n01 = P00*m01 + P01*m11;
        const float n10 = P10*m00 + P11*m10;
        const float n11 = P10*m01 + P11*m11;
        const bool ok = j < cnt;
        P00 = ok ? n00 : P00;
        P01 = ok ? n01 : P01;
        P10 = ok ? n10 : P10;
        P11 = ok ? n11 : P11;
    }

    // ---- phase 4: ordered log-tree combine, UNGUARDED ----
    // __shfl_down clamps OOB to self; lane 0's dependency cone (lanes off=2^k,
    // each needing lanes <= 63) never consumes a clamped value.
    #pragma unroll
    for (int off2 = 1; off2 < 64; off2 <<= 1) {
        const float q00 = __shfl_down(P00, off2);
        const float q01 = __shfl_down(P01, off2);
        const float q10 = __shfl_down(P10, off2);
        const float q11 = __shfl_down(P11, off2);
        const float n00 = P00*q00 + P01*q10;
        const float n01 = P00*q01 + P01*q11;
        const float n10 = P10*q00 + P11*q10;
        const float n11 = P10*q01 + P11*q11;
        P00 = n00; P01 = n01; P10 = n10; P11 = n11;
    }

    if (lane == 0) {
        // alpha0[j] = em[j][x0] * priors[j]
        const float a0 = (x0 ? em01 : em00) * p0;
        const float a1 = (x0 ? em11 : em10) * p1;
        const float v0 = a0*P00 + a1*P10;
        const float v1 = a0*P01 + a1*P11;
        out[b] = v0 + v1;
    }
}

extern "C" void kernel_launch(void* const* d_in, const int* in_sizes, int n_in,
                              void* d_out, int out_size, void* d_ws, size_t ws_size,
                              hipStream_t stream) {
    const int*   combined = (const int*)d_in[0];
    const float* sp       = (const float*)d_in[1];
    const float* tr       = (const float*)d_in[2];
    const float* emi      = (const float*)d_in[3];
    float* out = (float*)d_out;

    const int B = out_size;                 // 8192 sequences, one output each
    const int waves_per_block = 4;          // 256 threads
    const int grid = (B + waves_per_block - 1) / waves_per_block;
    hmm_fwd_kernel<<<grid, 256, 0, stream>>>(combined, sp, tr, emi, out, B);
}

// Round 2
// 100.837 us; speedup vs baseline: 1.0259x; 1.0096x over previous
//
#include <hip/hip_runtime.h>

// HMM forward, B=8192, TMAX=2048, N=2 states, obs in {0,1}.
// One wave (64 lanes) per sequence.
// R2 (this round): pair-step chain — falsification probe for BW-boundness.
//   - precompute Q[f][s] = M_f * M_s (4 two-step matrices, once per wave)
//   - chain walks 2 obs bits per iteration, divergent trip count nFull=cnt>>1
//     (exec-mask predication replaces 4 cndmask/iter), + predicated odd tail
//   - chain VALU ~660 -> ~360 cyc/wave; if dur_us doesn't move, kernel is
//     HBM-BW-bound (fetch ~34 MB ~= the int32 information floor) => roofline
// Carried from R1: W = ceil(steps/64) variable chunk width, per-word load
//   guards, ballot transpose + shfl/funnel redistribute, unguarded tree,
//   readfirstlane row base, 2x8-word pipelined load buffers.
#define TMAX_C 2048
#define ROWLEN (TMAX_C + 1)

__global__ __launch_bounds__(256, 8) void hmm_fwd_kernel(
    const int* __restrict__ combined,   // (B, TMAX+1): x[0..TMAX-1], T at [TMAX]
    const float* __restrict__ sp,       // (2,)  state prior logits
    const float* __restrict__ tr,       // (2,2) transition logits
    const float* __restrict__ emi,      // (2,2) emission logits
    float* __restrict__ out, int B)
{
    const int lane = threadIdx.x & 63;
    const int b = blockIdx.x * (blockDim.x >> 6) + (threadIdx.x >> 6);
    if (b >= B) return;

    // b is wave-uniform by construction; make it scalar so T/x0 are s_loads.
    const int ub = __builtin_amdgcn_readfirstlane(b);
    const int* __restrict__ row = combined + (size_t)ub * ROWLEN;
    const int T  = row[TMAX_C];          // gates everything; issue first
    const int x0 = row[0];
    const int steps = T - 1;             // matrices applied at t = 1 .. T-1
    const int W = (steps + 63) >> 6;     // per-lane chunk width == #64-obs words, 0..32

    // ---- phase 1: guarded pipelined loads + ballots ----
    // Word w covers obs-step bits [64w, 64w+64); lane loads element 1+64w+lane.
    unsigned wlo = 0u, whi = 0u;         // lane w (w<32) keeps ballot word w
    int A0[8], A1[8];

#define LOADG(g, buf)                                                   \
    do {                                                                \
        _Pragma("unroll")                                               \
        for (int u = 0; u < 8; ++u) {                                   \
            const int w = ((g) << 3) + u;                               \
            if (w < W) (buf)[u] = row[1 + (w << 6) + lane];             \
        }                                                               \
    } while (0)

#define BALLOTG(g, buf)                                                 \
    do {                                                                \
        _Pragma("unroll")                                               \
        for (int u = 0; u < 8; ++u) {                                   \
            const int w = ((g) << 3) + u;                               \
            if (w < W) {                                                \
                const unsigned long long m = __ballot((buf)[u] != 0);   \
                if (lane == w) {                                        \
                    wlo = (unsigned)m;                                  \
                    whi = (unsigned)(m >> 32);                          \
                }                                                       \
            }                                                           \
        }                                                               \
    } while (0)

    LOADG(0, A0);
    LOADG(1, A1);

    // ---- tiny softmaxes (overlap with outstanding loads) ----
    float p0 = __expf(sp[0]), p1 = __expf(sp[1]);
    { float s = p0 + p1; p0 /= s; p1 /= s; }
    float A00, A01, A10, A11;
    { float e0 = __expf(tr[0]), e1 = __expf(tr[1]); float s = e0 + e1; A00 = e0/s; A01 = e1/s; }
    { float e0 = __expf(tr[2]), e1 = __expf(tr[3]); float s = e0 + e1; A10 = e0/s; A11 = e1/s; }
    float em00, em01, em10, em11;   // em[state][obs]
    { float e0 = __expf(emi[0]), e1 = __expf(emi[1]); float s = e0 + e1; em00 = e0/s; em01 = e1/s; }
    { float e0 = __expf(emi[2]), e1 = __expf(emi[3]); float s = e0 + e1; em10 = e0/s; em11 = e1/s; }

    // M_o[i][j] = A[i][j] * em[j][o]   (row-vector convention)
    const float M0_00 = A00*em00, M0_01 = A01*em10, M0_10 = A10*em00, M0_11 = A11*em10;
    const float M1_00 = A00*em01, M1_01 = A01*em11, M1_10 = A10*em01, M1_11 = A11*em11;

    BALLOTG(0, A0);
    LOADG(2, A0);
    BALLOTG(1, A1);
    LOADG(3, A1);
    BALLOTG(2, A0);
    BALLOTG(3, A1);
#undef LOADG
#undef BALLOTG

    // ---- pair matrices Q[f][s] = M_f * M_s (after buffers die: low reg peak) ----
    const float Q00_00 = M0_00*M0_00 + M0_01*M0_10;
    const float Q00_01 = M0_00*M0_01 + M0_01*M0_11;
    const float Q00_10 = M0_10*M0_00 + M0_11*M0_10;
    const float Q00_11 = M0_10*M0_01 + M0_11*M0_11;

    const float Q01_00 = M0_00*M1_00 + M0_01*M1_10;   // first=0, second=1
    const float Q01_01 = M0_00*M1_01 + M0_01*M1_11;
    const float Q01_10 = M0_10*M1_00 + M0_11*M1_10;
    const float Q01_11 = M0_10*M1_01 + M0_11*M1_11;

    const float Q10_00 = M1_00*M0_00 + M1_01*M0_10;   // first=1, second=0
    const float Q10_01 = M1_00*M0_01 + M1_01*M0_11;
    const float Q10_10 = M1_10*M0_00 + M1_11*M0_10;
    const float Q10_11 = M1_10*M0_01 + M1_11*M0_11;

    const float Q11_00 = M1_00*M1_00 + M1_01*M1_10;
    const float Q11_01 = M1_00*M1_01 + M1_01*M1_11;
    const float Q11_10 = M1_10*M1_00 + M1_11*M1_10;
    const float Q11_11 = M1_10*M1_01 + M1_11*M1_11;

    // ---- phase 2: redistribute ballot words to per-lane W-bit windows ----
    // Lane L owns global obs-step bits [L*W, L*W+W).
    const int idx = lane * W;            // 0..2016
    const int w0  = idx >> 6;
    const int off = idx & 63;
    const unsigned u0lo = (unsigned)__shfl((int)wlo, w0);
    const unsigned u0hi = (unsigned)__shfl((int)whi, w0);
    const unsigned u1lo = (unsigned)__shfl((int)wlo, w0 + 1);  // lanes >=W hold 0
    const unsigned long long v64 = ((unsigned long long)u0hi << 32) | u0lo;
    unsigned bits = (unsigned)(v64 >> off);
    if (off + W > 64)                    // then off > 32, so 64-off in (0,32)
        bits |= (u1lo << (64 - off));

    int cnt = steps - idx;               // valid obs this lane, clamped to [0,W]
    cnt = cnt < 0 ? 0 : cnt;
    cnt = cnt > W ? W : cnt;

    // ---- phase 3: pair-step chain, divergent trip nFull = cnt>>1 ----
    float P00 = 1.f, P01 = 0.f, P10 = 0.f, P11 = 1.f;
    const int nFull = cnt >> 1;
    #pragma unroll 2
    for (int j = 0; j < nFull; ++j) {
        const unsigned pi = (bits >> (j << 1)) & 3u;  // bit0=first obs, bit1=second
        const bool f = (pi & 1u) != 0u;
        const bool s = (pi & 2u) != 0u;
        const float m00 = s ? (f ? Q11_00 : Q01_00) : (f ? Q10_00 : Q00_00);
        const float m01 = s ? (f ? Q11_01 : Q01_01) : (f ? Q10_01 : Q00_01);
        const float m10 = s ? (f ? Q11_10 : Q01_10) : (f ? Q10_10 : Q00_10);
        const float m11 = s ? (f ? Q11_11 : Q01_11) : (f ? Q10_11 : Q00_11);
        const float n00 = P00*m00 + P01*m10;
        const float n01 = P00*m01 + P01*m11;
        const float n10 = P10*m00 + P11*m10;
        const float n11 = P10*m01 + P11*m11;
        P00 = n00; P01 = n01; P10 = n10; P11 = n11;
    }
    // odd tail: one predicated single step at bit position cnt-1
    {
        const bool odd = (cnt & 1) != 0;
        const unsigned tb = (bits >> ((cnt - 1) & 31)) & 1u;
        const float m00 = tb ? M1_00 : M0_00;
        const float m01 = tb ? M1_01 : M0_01;
        const float m10 = tb ? M1_10 : M0_10;
        const float m11 = tb ? M1_11 : M0_11;
        const float n00 = P00*m00 + P01*m10;
        const float n01 = P00*m01 + P01*m11;
        const float n10 = P10*m00 + P11*m10;
        const float n11 = P10*m01 + P11*m11;
        P00 = odd ? n00 : P00;
        P01 = odd ? n01 : P01;
        P10 = odd ? n10 : P10;
        P11 = odd ? n11 : P11;
    }

    // ---- phase 4: ordered log-tree combine, UNGUARDED ----
    // __shfl_down clamps OOB to self; lane 0's dependency cone (lanes off=2^k,
    // each needing lanes <= 63) never consumes a clamped value.
    #pragma unroll
    for (int off2 = 1; off2 < 64; off2 <<= 1) {
        const float q00 = __shfl_down(P00, off2);
        const float q01 = __shfl_down(P01, off2);
        const float q10 = __shfl_down(P10, off2);
        const float q11 = __shfl_down(P11, off2);
        const float n00 = P00*q00 + P01*q10;
        const float n01 = P00*q01 + P01*q11;
        const float n10 = P10*q00 + P11*q10;
        const float n11 = P10*q01 + P11*q11;
        P00 = n00; P01 = n01; P10 = n10; P11 = n11;
    }

    if (lane == 0) {
        // alpha0[j] = em[j][x0] * priors[j]
        const float a0 = (x0 ? em01 : em00) * p0;
        const float a1 = (x0 ? em11 : em10) * p1;
        const float v0 = a0*P00 + a1*P10;
        const float v1 = a0*P01 + a1*P11;
        out[b] = v0 + v1;
    }
}

extern "C" void kernel_launch(void* const* d_in, const int* in_sizes, int n_in,
                              void* d_out, int out_size, void* d_ws, size_t ws_size,
                              hipStream_t stream) {
    const int*   combined = (const int*)d_in[0];
    const float* sp       = (const float*)d_in[1];
    const float* tr       = (const float*)d_in[2];
    const float* emi      = (const float*)d_in[3];
    float* out = (float*)d_out;

    const int B = out_size;                 // 8192 sequences, one output each
    const int waves_per_block = 4;          // 256 threads
    const int grid = (B + waves_per_block - 1) / waves_per_block;
    hmm_fwd_kernel<<<grid, 256, 0, stream>>>(combined, sp, tr, emi, out, B);
}

// Round 4
// 100.313 us; speedup vs baseline: 1.0313x; 1.0052x over previous
//
#include <hip/hip_runtime.h>

// HMM forward, B=8192, TMAX=2048, N=2 states, obs in {0,1}.
// One wave (64 lanes) per sequence.
// R4 (this round): R3 retry without the writelane builtin (not available on
// this ROCm; compile error). Sole change vs R2:
//   - words 0..7 loaded UNGUARDED and issued alongside the scalar T load:
//     removes the T->x-load serialization (two in-phase ~900cy stalls -> one).
//     Extra fetch only for rows with T<450 (~0.5 MB total, +0.08 us BW).
//   - per-group SGPR base pointers so load imm offsets fit 13-bit signed.
// Ballot keep stays the R1/R2-proven predicated form (if lane==w -> cndmask).
// Carried from R2: pair-step chain with Q[f][s] 2-step matrices, divergent
//   trip nFull, predicated odd tail. From R1: W=ceil(steps/64) chunking,
//   ballot transpose + shfl/funnel redistribute, unguarded shfl tree,
//   readfirstlane row base, 2x8-word pipelined buffers.
#define TMAX_C 2048
#define ROWLEN (TMAX_C + 1)

__global__ __launch_bounds__(256, 8) void hmm_fwd_kernel(
    const int* __restrict__ combined,   // (B, TMAX+1): x[0..TMAX-1], T at [TMAX]
    const float* __restrict__ sp,       // (2,)  state prior logits
    const float* __restrict__ tr,       // (2,2) transition logits
    const float* __restrict__ emi,      // (2,2) emission logits
    float* __restrict__ out, int B)
{
    const int lane = threadIdx.x & 63;
    const int b = blockIdx.x * (blockDim.x >> 6) + (threadIdx.x >> 6);
    if (b >= B) return;

    // b is wave-uniform by construction; make it scalar so T/x0 are s_loads.
    const int ub = __builtin_amdgcn_readfirstlane(b);
    const int* __restrict__ row = combined + (size_t)ub * ROWLEN;
    const int T  = row[TMAX_C];          // scalar load; gates guards below
    const int x0 = row[0];

    // ---- words 0..7: UNGUARDED, in flight with the T load ----
    // Max address row[1+7*64+63] = row[512] <= row[2048]: always in-bounds.
    int A0[8], A1[8];
    {
        const int* __restrict__ rg = row + 1;
        #pragma unroll
        for (int u = 0; u < 8; ++u) A0[u] = rg[(u << 6) + lane];
    }

    // ---- tiny softmaxes (overlap with outstanding loads) ----
    float p0 = __expf(sp[0]), p1 = __expf(sp[1]);
    { float s = p0 + p1; p0 /= s; p1 /= s; }
    float A00, A01, A10, A11;
    { float e0 = __expf(tr[0]), e1 = __expf(tr[1]); float s = e0 + e1; A00 = e0/s; A01 = e1/s; }
    { float e0 = __expf(tr[2]), e1 = __expf(tr[3]); float s = e0 + e1; A10 = e0/s; A11 = e1/s; }
    float em00, em01, em10, em11;   // em[state][obs]
    { float e0 = __expf(emi[0]), e1 = __expf(emi[1]); float s = e0 + e1; em00 = e0/s; em01 = e1/s; }
    { float e0 = __expf(emi[2]), e1 = __expf(emi[3]); float s = e0 + e1; em10 = e0/s; em11 = e1/s; }

    // M_o[i][j] = A[i][j] * em[j][o]   (row-vector convention)
    const float M0_00 = A00*em00, M0_01 = A01*em10, M0_10 = A10*em00, M0_11 = A11*em10;
    const float M1_00 = A00*em01, M1_01 = A01*em11, M1_10 = A10*em01, M1_11 = A11*em11;

    const int steps = T - 1;             // matrices applied at t = 1 .. T-1
    const int W = (steps + 63) >> 6;     // per-lane chunk width == #64-obs words, 0..32

    // ---- guarded loads (words 8+) + ballots, pipelined 2x8 buffers ----
    // Word w covers obs-step bits [64w, 64w+64); lane loads element 1+64w+lane.
    unsigned wlo = 0u, whi = 0u;         // lane w (w<32) keeps ballot word w

#define LOADG(g, buf)                                                   \
    do {                                                                \
        const int* __restrict__ rg = row + 1 + ((g) << 9);              \
        _Pragma("unroll")                                               \
        for (int u = 0; u < 8; ++u) {                                   \
            const int w = ((g) << 3) + u;                               \
            if (w < W) (buf)[u] = rg[(u << 6) + lane];                  \
        }                                                               \
    } while (0)

#define BALLOTG(g, buf)                                                 \
    do {                                                                \
        _Pragma("unroll")                                               \
        for (int u = 0; u < 8; ++u) {                                   \
            const int w = ((g) << 3) + u;                               \
            if (w < W) {                                                \
                const unsigned long long m = __ballot((buf)[u] != 0);   \
                if (lane == w) {                                        \
                    wlo = (unsigned)m;                                  \
                    whi = (unsigned)(m >> 32);                          \
                }                                                       \
            }                                                           \
        }                                                               \
    } while (0)

    LOADG(1, A1);
    BALLOTG(0, A0);
    LOADG(2, A0);
    BALLOTG(1, A1);
    LOADG(3, A1);
    BALLOTG(2, A0);
    BALLOTG(3, A1);
#undef LOADG
#undef BALLOTG

    // ---- pair matrices Q[f][s] = M_f * M_s (after buffers die: low reg peak) ----
    const float Q00_00 = M0_00*M0_00 + M0_01*M0_10;
    const float Q00_01 = M0_00*M0_01 + M0_01*M0_11;
    const float Q00_10 = M0_10*M0_00 + M0_11*M0_10;
    const float Q00_11 = M0_10*M0_01 + M0_11*M0_11;

    const float Q01_00 = M0_00*M1_00 + M0_01*M1_10;   // first=0, second=1
    const float Q01_01 = M0_00*M1_01 + M0_01*M1_11;
    const float Q01_10 = M0_10*M1_00 + M0_11*M1_10;
    const float Q01_11 = M0_10*M1_01 + M0_11*M1_11;

    const float Q10_00 = M1_00*M0_00 + M1_01*M0_10;   // first=1, second=0
    const float Q10_01 = M1_00*M0_01 + M1_01*M0_11;
    const float Q10_10 = M1_10*M0_00 + M1_11*M0_10;
    const float Q10_11 = M1_10*M0_01 + M1_11*M0_11;

    const float Q11_00 = M1_00*M1_00 + M1_01*M1_10;
    const float Q11_01 = M1_00*M1_01 + M1_01*M1_11;
    const float Q11_10 = M1_10*M1_00 + M1_11*M1_10;
    const float Q11_11 = M1_10*M1_01 + M1_11*M1_11;

    // ---- redistribute ballot words to per-lane W-bit windows ----
    // Lane L owns global obs-step bits [L*W, L*W+W).
    const int idx = lane * W;            // 0..2016
    const int w0  = idx >> 6;
    const int off = idx & 63;
    const unsigned u0lo = (unsigned)__shfl((int)wlo, w0);
    const unsigned u0hi = (unsigned)__shfl((int)whi, w0);
    const unsigned u1lo = (unsigned)__shfl((int)wlo, w0 + 1);  // lanes >=W hold 0
    const unsigned long long v64 = ((unsigned long long)u0hi << 32) | u0lo;
    unsigned bits = (unsigned)(v64 >> off);
    if (off + W > 64)                    // then off > 32, so 64-off in (0,32)
        bits |= (u1lo << (64 - off));

    int cnt = steps - idx;               // valid obs this lane, clamped to [0,W]
    cnt = cnt < 0 ? 0 : cnt;
    cnt = cnt > W ? W : cnt;

    // ---- pair-step chain, divergent trip nFull = cnt>>1 ----
    float P00 = 1.f, P01 = 0.f, P10 = 0.f, P11 = 1.f;
    const int nFull = cnt >> 1;
    #pragma unroll 2
    for (int j = 0; j < nFull; ++j) {
        const unsigned pi = (bits >> (j << 1)) & 3u;  // bit0=first obs, bit1=second
        const bool f = (pi & 1u) != 0u;
        const bool s = (pi & 2u) != 0u;
        const float m00 = s ? (f ? Q11_00 : Q01_00) : (f ? Q10_00 : Q00_00);
        const float m01 = s ? (f ? Q11_01 : Q01_01) : (f ? Q10_01 : Q00_01);
        const float m10 = s ? (f ? Q11_10 : Q01_10) : (f ? Q10_10 : Q00_10);
        const float m11 = s ? (f ? Q11_11 : Q01_11) : (f ? Q10_11 : Q00_11);
        const float n00 = P00*m00 + P01*m10;
        const float n01 = P00*m01 + P01*m11;
        const float n10 = P10*m00 + P11*m10;
        const float n11 = P10*m01 + P11*m11;
        P00 = n00; P01 = n01; P10 = n10; P11 = n11;
    }
    // odd tail: one predicated single step at bit position cnt-1
    {
        const bool odd = (cnt & 1) != 0;
        const unsigned tb = (bits >> ((cnt - 1) & 31)) & 1u;
        const float m00 = tb ? M1_00 : M0_00;
        const float m01 = tb ? M1_01 : M0_01;
        const float m10 = tb ? M1_10 : M0_10;
        const float m11 = tb ? M1_11 : M0_11;
        const float n00 = P00*m00 + P01*m10;
        const float n01 = P00*m01 + P01*m11;
        const float n10 = P10*m00 + P11*m10;
        const float n11 = P10*m01 + P11*m11;
        P00 = odd ? n00 : P00;
        P01 = odd ? n01 : P01;
        P10 = odd ? n10 : P10;
        P11 = odd ? n11 : P11;
    }

    // ---- ordered log-tree combine, UNGUARDED ----
    // __shfl_down clamps OOB to self; lane 0's dependency cone (lanes off=2^k,
    // each needing lanes <= 63) never consumes a clamped value.
    #pragma unroll
    for (int off2 = 1; off2 < 64; off2 <<= 1) {
        const float q00 = __shfl_down(P00, off2);
        const float q01 = __shfl_down(P01, off2);
        const float q10 = __shfl_down(P10, off2);
        const float q11 = __shfl_down(P11, off2);
        const float n00 = P00*q00 + P01*q10;
        const float n01 = P00*q01 + P01*q11;
        const float n10 = P10*q00 + P11*q10;
        const float n11 = P10*q01 + P11*q11;
        P00 = n00; P01 = n01; P10 = n10; P11 = n11;
    }

    if (lane == 0) {
        // alpha0[j] = em[j][x0] * priors[j]
        const float a0 = (x0 ? em01 : em00) * p0;
        const float a1 = (x0 ? em11 : em10) * p1;
        const float v0 = a0*P00 + a1*P10;
        const float v1 = a0*P01 + a1*P11;
        out[b] = v0 + v1;
    }
}

extern "C" void kernel_launch(void* const* d_in, const int* in_sizes, int n_in,
                              void* d_out, int out_size, void* d_ws, size_t ws_size,
                              hipStream_t stream) {
    const int*   combined = (const int*)d_in[0];
    const float* sp       = (const float*)d_in[1];
    const float* tr       = (const float*)d_in[2];
    const float* emi      = (const float*)d_in[3];
    float* out = (float*)d_out;

    const int B = out_size;                 // 8192 sequences, one output each
    const int waves_per_block = 4;          // 256 threads
    const int grid = (B + waves_per_block - 1) / waves_per_block;
    hmm_fwd_kernel<<<grid, 256, 0, stream>>>(combined, sp, tr, emi, out, B);
}